// Round 1
// baseline (134.617 us; speedup 1.0000x reference)
//
#include <hip/hip_runtime.h>

typedef unsigned short u16;
typedef __attribute__((ext_vector_type(8))) __bf16 bf16x8;
typedef __attribute__((ext_vector_type(8))) unsigned short u16x8;
typedef __attribute__((ext_vector_type(4))) float f32x4;

__device__ __forceinline__ u16 f2bf(float f) {
  unsigned u = __builtin_bit_cast(unsigned, f);
  unsigned r = u + 0x7fffu + ((u >> 16) & 1u);
  return (u16)(r >> 16);
}

__device__ __forceinline__ float wave_sum(float v) {
#pragma unroll
  for (int o = 32; o; o >>= 1) v += __shfl_xor(v, o, 64);
  return v;
}

__device__ __forceinline__ bf16x8 bzero() {
  bf16x8 z;
#pragma unroll
  for (int i = 0; i < 8; ++i) z[i] = (__bf16)0.0f;
  return z;
}

// ---------------- P0: per-(b,c) spatial sum of source_enc ----------------
__global__ void k_plane_sum(const float* __restrict__ src, float* __restrict__ ssum) {
  int plane = blockIdx.x;               // 1024 = 4*256
  const float* p = src + (size_t)plane * 4096;
  int t = threadIdx.x;
  float s = 0.f;
#pragma unroll
  for (int i = 0; i < 4; ++i) {
    f32x4 v = *(const f32x4*)(p + (i * 256 + t) * 4);
    s += v[0] + v[1] + v[2] + v[3];
  }
  s = wave_sum(s);
  __shared__ float red[4];
  if ((t & 63) == 0) red[t >> 6] = s;
  __syncthreads();
  if (t == 0) ssum[plane] = red[0] + red[1] + red[2] + red[3];
}

// ---------------- P1: small algebra: dvec[b][c], G[o2][c] ----------------
__global__ void k_small(const float* __restrict__ ssum,
                        const float* __restrict__ qw, const float* __restrict__ qb,
                        const float* __restrict__ kw, const float* __restrict__ kb,
                        const float* __restrict__ lw, const float* __restrict__ lb,
                        const float* __restrict__ aw, const float* __restrict__ ab,
                        const float* __restrict__ gamma,
                        float* __restrict__ dvec, float* __restrict__ G) {
  __shared__ float qs_l[128], amap_l[128];
  int t = threadIdx.x;
  if (t < 128) {                        // q.sum(hw) via ssum
    int b = t >> 5, o = t & 31;
    float s = 4096.f * qb[o];
    for (int c = 0; c < 256; ++c) s += qw[o * 256 + c] * ssum[b * 256 + c];
    qs_l[t] = s;
  }
  __syncthreads();
  if (t < 128) {                        // amap_const[b][o2]
    int b = t >> 5, o2 = t & 31;
    float s = 0.f, kt = 0.f;
    for (int o = 0; o < 32; ++o) {
      s += lw[o2 * 64 + 32 + o] * qs_l[b * 32 + o];
      kt += lw[o2 * 64 + o] * kb[o];
    }
    amap_l[t] = 4096.f * (kt + lb[o2]) + s;
  }
  __syncthreads();
  float g = gamma[0];
  for (int i = t; i < 1024; i += 256) { // d[b][c] = gamma*cv
    int b = i >> 8, c = i & 255;
    float s = ab[c];
    for (int o2 = 0; o2 < 32; ++o2) s += aw[c * 288 + 256 + o2] * amap_l[b * 32 + o2];
    dvec[i] = g * s;
  }
  for (int i = t; i < 8192; i += 256) { // G = Wk @ key_w
    int o2 = i >> 8, c = i & 255;
    float s = 0.f;
    for (int a = 0; a < 32; ++a) s += lw[o2 * 64 + a] * kw[a * 256 + c];
    G[i] = s;
  }
}

// ---------------- P2: Mt = I + gamma*(A1 + WH*A2@G) ----------------
__global__ void k_Mt(const float* __restrict__ aw, const float* __restrict__ G,
                     const float* __restrict__ gamma, float* __restrict__ Mt) {
  int o = blockIdx.x, c = threadIdx.x;
  __shared__ float a2[32];
  if (c < 32) a2[c] = aw[o * 288 + 256 + c];
  __syncthreads();
  float s = 0.f;
  for (int o2 = 0; o2 < 32; ++o2) s += a2[o2] * G[o2 * 256 + c];
  Mt[o * 256 + c] = gamma[0] * (aw[o * 288 + c] + 4096.f * s) + (o == c ? 1.f : 0.f);
}

// ---------------- P3: folded conv weights w3 (bf16) + cd2 constants ----------------
// w3 layout: idx(tap,cg,kbq,oc,j) = (((tap*16+cg)*4+kbq)*128+oc)*8+j  for channel cf=cg*32+kbq*8+j
__global__ void k_w3(const float* __restrict__ cw, const float* __restrict__ Mt,
                     const float* __restrict__ dvec, u16* __restrict__ w3,
                     float* __restrict__ cd2) {
  int blk = blockIdx.x;                 // 1152 = 9*128
  int tap = blk / 128, oc = blk % 128;
  int tid = threadIdx.x;
  __shared__ float cwl[512];
  for (int c = tid; c < 512; c += 256) cwl[c] = cw[(size_t)(oc * 512 + c) * 9 + tap];
  __syncthreads();
  int c2 = tid;
  float s = 0.f;
  for (int c = 0; c < 256; ++c) s += cwl[c] * Mt[c * 256 + c2];
  {
    int cf = c2;
    int cg = cf >> 5, kbq = (cf >> 3) & 3, j = cf & 7;
    w3[((((tap * 16 + cg) * 4 + kbq) * 128 + oc) << 3) + j] = f2bf(s);
    cf = c2 + 256;
    cg = cf >> 5; kbq = (cf >> 3) & 3; j = cf & 7;
    w3[((((tap * 16 + cg) * 4 + kbq) * 128 + oc) << 3) + j] = f2bf(cwl[c2 + 256]);
  }
  __shared__ float red[4];
  for (int b = 0; b < 4; ++b) {
    float p = cwl[tid] * dvec[b * 256 + tid];   // only channels 0..255 carry d
    p = wave_sum(p);
    if ((tid & 63) == 0) red[tid >> 6] = p;
    __syncthreads();
    if (tid == 0) cd2[(size_t)(b * 128 + oc) * 9 + tap] = red[0] + red[1] + red[2] + red[3];
    __syncthreads();
  }
}

// ---------------- X: build NHWC bf16 xin[b][h][w][512] ----------------
__global__ void k_xin(const float* __restrict__ tgt, const float* __restrict__ prev,
                      u16* __restrict__ xin) {
  int b = blockIdx.x >> 6, h = blockIdx.x & 63;
  __shared__ u16 lt[256 * 66];
  int tid = threadIdx.x;
  const float* tp = tgt + ((size_t)(b * 256) * 64 + h) * 64;
  u16* xp = xin + (((size_t)(b * 64) + h) * 64) * 512;
  // phase A: target rows -> LDS [c][w]
  for (int it = 0; it < 16; ++it) {
    int fi = it * 256 + tid;
    int c = fi >> 4, w4 = fi & 15;
    f32x4 v = *(const f32x4*)(tp + (size_t)c * 4096 + w4 * 4);
    int base = c * 66 + w4 * 4;
    lt[base] = f2bf(v[0]); lt[base + 1] = f2bf(v[1]);
    lt[base + 2] = f2bf(v[2]); lt[base + 3] = f2bf(v[3]);
  }
  __syncthreads();
  // write channels 0..255 transposed (coalesced, channel-contiguous)
  for (int it = 0; it < 8; ++it) {
    int i = it * 256 + tid;
    int c8 = i & 31, w = i >> 5;
    u16x8 v;
#pragma unroll
    for (int k = 0; k < 8; ++k) v[k] = lt[(c8 * 8 + k) * 66 + w];
    *(u16x8*)(xp + (size_t)w * 512 + c8 * 8) = v;
  }
  __syncthreads();
  // phase B: prev upsample -> LDS [cc][w]
  const float* pp = prev + ((size_t)(b * 256) * 32 + (h >> 1)) * 32;
  for (int it = 0; it < 8; ++it) {
    int pi = it * 256 + tid;
    int cc = pi >> 3, wq = pi & 7;
    f32x4 v = *(const f32x4*)(pp + (size_t)cc * 1024 + wq * 4);
    int base = cc * 66 + wq * 8;
    u16 b0 = f2bf(v[0]), b1 = f2bf(v[1]), b2 = f2bf(v[2]), b3 = f2bf(v[3]);
    lt[base] = b0; lt[base + 1] = b0; lt[base + 2] = b1; lt[base + 3] = b1;
    lt[base + 4] = b2; lt[base + 5] = b2; lt[base + 6] = b3; lt[base + 7] = b3;
  }
  __syncthreads();
  // write channels 256..511
  for (int it = 0; it < 8; ++it) {
    int i = it * 256 + tid;
    int c8 = i & 31, w = i >> 5;
    u16x8 v;
#pragma unroll
    for (int k = 0; k < 8; ++k) v[k] = lt[(c8 * 8 + k) * 66 + w];
    *(u16x8*)(xp + (size_t)w * 512 + 256 + c8 * 8) = v;
  }
}

// ---------------- C: tap-decomposed implicit-im2col MFMA conv ----------------
// block = (b, h0). M=128 oc x N=64 px, K = 16 cgroups x 9 taps x 32 ch.
__global__ __launch_bounds__(256) void k_conv(const u16* __restrict__ xin,
                                              const u16* __restrict__ w3,
                                              const float* __restrict__ cd2,
                                              float* __restrict__ out) {
  __shared__ u16 lds[2 * 3 * 64 * 32];   // 24KB, double buffered
  int b = blockIdx.x >> 6, h0 = blockIdx.x & 63;
  int tid = threadIdx.x, l = tid & 63, wv = tid >> 6;
  int wr = wv >> 1, wc = wv & 1;          // wave tile: M 64 x N 32
  const int r = l & 15, kb4 = l >> 4;

  if (h0 == 0)
    for (int i = tid; i < 2048; i += 256) { lds[i] = 0; lds[6144 + i] = 0; }
  if (h0 == 63)
    for (int i = tid; i < 2048; i += 256) { lds[4096 + i] = 0; lds[6144 + 4096 + i] = 0; }

  auto STAGE = [&](int buf, int cg) {
    u16x8 tmp[3]; int dsts[3]; bool doit[3];
#pragma unroll
    for (int i = 0; i < 3; ++i) {
      int chunk = wv * 3 + i, dy = chunk >> 2, qd = chunk & 3;
      int grow = h0 - 1 + dy;
      int px = qd * 16 + (l >> 2), sub = l & 3;
      int kb = sub ^ ((px >> 1) & 3);     // source-side swizzle
      doit[i] = ((unsigned)grow < 64u);
      if (doit[i])
        tmp[i] = *(const u16x8*)(xin + ((((size_t)(b * 64) + grow) * 64 + px) * 512 + cg * 32 + kb * 8));
      dsts[i] = buf * 6144 + dy * 2048 + px * 32 + sub * 8;
    }
#pragma unroll
    for (int i = 0; i < 3; ++i)
      if (doit[i]) *(u16x8*)(lds + dsts[i]) = tmp[i];
  };

  f32x4 acc[4][2];
  const f32x4 fz = {0.f, 0.f, 0.f, 0.f};
#pragma unroll
  for (int mf = 0; mf < 4; ++mf)
#pragma unroll
    for (int nf = 0; nf < 2; ++nf) acc[mf][nf] = fz;

  STAGE(0, 0);
  int cur = 0;
  for (int cg = 0; cg < 16; ++cg) {
    __syncthreads();
    if (cg < 15) STAGE(cur ^ 1, cg + 1);
    const u16* L = lds + cur * 6144;
#pragma unroll
    for (int t = 0; t < 9; ++t) {
      const int dy = t / 3, dx = t % 3;
      bf16x8 av[4];
#pragma unroll
      for (int mf = 0; mf < 4; ++mf)
        av[mf] = *(const bf16x8*)(w3 + ((((t * 16 + cg) * 4 + kb4) * 128 + wr * 64 + mf * 16 + r) << 3));
      bf16x8 bv[2];
#pragma unroll
      for (int nf = 0; nf < 2; ++nf) {
        int sx = wc * 32 + nf * 16 + r + dx - 1;
        bf16x8 z = bzero();
        if ((unsigned)sx < 64u) {
          int slot = kb4 ^ ((sx >> 1) & 3); // read-side swizzle
          z = *(const bf16x8*)(L + dy * 2048 + sx * 32 + slot * 8);
        }
        bv[nf] = z;
      }
#pragma unroll
      for (int mf = 0; mf < 4; ++mf)
#pragma unroll
        for (int nf = 0; nf < 2; ++nf)
          acc[mf][nf] = __builtin_amdgcn_mfma_f32_16x16x32_bf16(av[mf], bv[nf], acc[mf][nf], 0, 0, 0);
    }
    cur ^= 1;
  }

  // epilogue: add border-masked constant contribution, store y (pre-norm)
  bool dy0v = (h0 > 0), dy2v = (h0 < 63);
#pragma unroll
  for (int mf = 0; mf < 4; ++mf) {
#pragma unroll
    for (int j = 0; j < 4; ++j) {
      int oc = wr * 64 + mf * 16 + kb4 * 4 + j;
      const float* cd = cd2 + (size_t)(b * 128 + oc) * 9;
      float sAll = 0.f, sL = 0.f, sR = 0.f;
#pragma unroll
      for (int dy = 0; dy < 3; ++dy) {
        bool v = (dy == 1) || (dy == 0 ? dy0v : dy2v);
        if (v) {
          sAll += cd[dy * 3] + cd[dy * 3 + 1] + cd[dy * 3 + 2];
          sL += cd[dy * 3];
          sR += cd[dy * 3 + 2];
        }
      }
#pragma unroll
      for (int nf = 0; nf < 2; ++nf) {
        int px = wc * 32 + nf * 16 + r;
        float corr = sAll - (px == 0 ? sL : 0.f) - (px == 63 ? sR : 0.f);
        out[(((size_t)(b * 128 + oc)) * 64 + h0) * 64 + px] = acc[mf][nf][j] + corr;
      }
    }
  }
}

// ---------------- N: in-place instance norm + relu ----------------
__global__ void k_norm(float* __restrict__ out) {
  int plane = blockIdx.x;               // 512 = 4*128
  float* p = out + (size_t)plane * 4096;
  int t = threadIdx.x;
  f32x4 v[4];
  float s = 0.f, s2 = 0.f;
#pragma unroll
  for (int i = 0; i < 4; ++i) {
    v[i] = *(const f32x4*)(p + (i * 256 + t) * 4);
#pragma unroll
    for (int k = 0; k < 4; ++k) { s += v[i][k]; s2 += v[i][k] * v[i][k]; }
  }
  s = wave_sum(s); s2 = wave_sum(s2);
  __shared__ float rs[4], rs2[4];
  if ((t & 63) == 0) { rs[t >> 6] = s; rs2[t >> 6] = s2; }
  __syncthreads();
  float S = rs[0] + rs[1] + rs[2] + rs[3];
  float S2 = rs2[0] + rs2[1] + rs2[2] + rs2[3];
  float mean = S * (1.f / 4096.f);
  float var = S2 * (1.f / 4096.f) - mean * mean;
  float inv = rsqrtf(var + 1e-5f);
#pragma unroll
  for (int i = 0; i < 4; ++i) {
    f32x4 o;
#pragma unroll
    for (int k = 0; k < 4; ++k) {
      float y = (v[i][k] - mean) * inv;
      o[k] = y > 0.f ? y : 0.f;
    }
    *(f32x4*)(p + (i * 256 + t) * 4) = o;
  }
}

extern "C" void kernel_launch(void* const* d_in, const int* in_sizes, int n_in,
                              void* d_out, int out_size, void* d_ws, size_t ws_size,
                              hipStream_t stream) {
  const float* src    = (const float*)d_in[0];
  const float* tgt    = (const float*)d_in[1];
  const float* prev   = (const float*)d_in[2];
  const float* key_w  = (const float*)d_in[3];
  const float* key_b  = (const float*)d_in[4];
  const float* qry_w  = (const float*)d_in[5];
  const float* qry_b  = (const float*)d_in[6];
  const float* lin_w  = (const float*)d_in[7];
  const float* lin_b  = (const float*)d_in[8];
  const float* attn_w = (const float*)d_in[9];
  const float* attn_b = (const float*)d_in[10];
  const float* gamma  = (const float*)d_in[11];
  const float* conv_w = (const float*)d_in[12];
  // d_in[13] = conv_b: dropped — a per-(b,oc) constant cancels under instance norm.

  char* ws = (char*)d_ws;
  size_t off = 0;
  u16*   xin  = (u16*)(ws + off);  off += 16777216;            // 4*64*64*512 bf16
  float* ssum = (float*)(ws + off); off += 4096;               // 4*256
  float* dvec = (float*)(ws + off); off += 4096;               // 4*256
  float* G    = (float*)(ws + off); off += 32768;              // 32*256
  float* Mt   = (float*)(ws + off); off += 262144;             // 256*256
  float* cd2  = (float*)(ws + off); off += 18432;              // 4*128*9
  u16*   w3   = (u16*)(ws + off);  off += 1179648;             // 9*16*4*128*8 bf16
  float* out  = (float*)d_out;

  k_plane_sum<<<1024, 256, 0, stream>>>(src, ssum);
  k_small<<<1, 256, 0, stream>>>(ssum, qry_w, qry_b, key_w, key_b, lin_w, lin_b,
                                 attn_w, attn_b, gamma, dvec, G);
  k_Mt<<<256, 256, 0, stream>>>(attn_w, G, gamma, Mt);
  k_w3<<<1152, 256, 0, stream>>>(conv_w, Mt, dvec, w3, cd2);
  k_xin<<<256, 256, 0, stream>>>(tgt, prev, xin);
  k_conv<<<256, 256, 0, stream>>>(xin, w3, cd2, out);
  k_norm<<<512, 256, 0, stream>>>(out);
}

// Round 2
// 108.392 us; speedup vs baseline: 1.2419x; 1.2419x over previous
//
#include <hip/hip_runtime.h>

typedef unsigned short u16;
typedef __attribute__((ext_vector_type(8))) __bf16 bf16x8;
typedef __attribute__((ext_vector_type(8))) unsigned short u16x8;
typedef __attribute__((ext_vector_type(4))) float f32x4;

__device__ __forceinline__ u16 f2bf(float f) {
  unsigned u = __builtin_bit_cast(unsigned, f);
  unsigned r = u + 0x7fffu + ((u >> 16) & 1u);
  return (u16)(r >> 16);
}

__device__ __forceinline__ float wave_sum(float v) {
#pragma unroll
  for (int o = 32; o; o >>= 1) v += __shfl_xor(v, o, 64);
  return v;
}

__device__ __forceinline__ bf16x8 bzero() {
  bf16x8 z;
#pragma unroll
  for (int i = 0; i < 8; ++i) z[i] = (__bf16)0.0f;
  return z;
}

// ---------------- P0: per-(b,c) spatial sum of source_enc ----------------
__global__ void k_plane_sum(const float* __restrict__ src, float* __restrict__ ssum) {
  int plane = blockIdx.x;               // 1024 = 4*256
  const float* p = src + (size_t)plane * 4096;
  int t = threadIdx.x;
  float s = 0.f;
#pragma unroll
  for (int i = 0; i < 4; ++i) {
    f32x4 v = *(const f32x4*)(p + (i * 256 + t) * 4);
    s += v[0] + v[1] + v[2] + v[3];
  }
  s = wave_sum(s);
  __shared__ float red[4];
  if ((t & 63) == 0) red[t >> 6] = s;
  __syncthreads();
  if (t == 0) ssum[plane] = red[0] + red[1] + red[2] + red[3];
}

// ---------------- P1: small algebra: dvec[b][c], G[o2][c] ----------------
__global__ void k_small(const float* __restrict__ ssum,
                        const float* __restrict__ qw, const float* __restrict__ qb,
                        const float* __restrict__ kw, const float* __restrict__ kb,
                        const float* __restrict__ lw, const float* __restrict__ lb,
                        const float* __restrict__ aw, const float* __restrict__ ab,
                        const float* __restrict__ gamma,
                        float* __restrict__ dvec, float* __restrict__ G) {
  __shared__ float qs_l[128], amap_l[128];
  int t = threadIdx.x;
  if (t < 128) {                        // q.sum(hw) via ssum
    int b = t >> 5, o = t & 31;
    float s = 4096.f * qb[o];
    for (int c = 0; c < 256; ++c) s += qw[o * 256 + c] * ssum[b * 256 + c];
    qs_l[t] = s;
  }
  __syncthreads();
  if (t < 128) {                        // amap_const[b][o2]
    int b = t >> 5, o2 = t & 31;
    float s = 0.f, kt = 0.f;
    for (int o = 0; o < 32; ++o) {
      s += lw[o2 * 64 + 32 + o] * qs_l[b * 32 + o];
      kt += lw[o2 * 64 + o] * kb[o];
    }
    amap_l[t] = 4096.f * (kt + lb[o2]) + s;
  }
  __syncthreads();
  float g = gamma[0];
  for (int i = t; i < 1024; i += 256) { // d[b][c] = gamma*cv
    int b = i >> 8, c = i & 255;
    float s = ab[c];
    for (int o2 = 0; o2 < 32; ++o2) s += aw[c * 288 + 256 + o2] * amap_l[b * 32 + o2];
    dvec[i] = g * s;
  }
  for (int i = t; i < 8192; i += 256) { // G = Wk @ key_w
    int o2 = i >> 8, c = i & 255;
    float s = 0.f;
    for (int a = 0; a < 32; ++a) s += lw[o2 * 64 + a] * kw[a * 256 + c];
    G[i] = s;
  }
}

// ---------------- P2: Mt = I + gamma*(A1 + WH*A2@G) ----------------
__global__ void k_Mt(const float* __restrict__ aw, const float* __restrict__ G,
                     const float* __restrict__ gamma, float* __restrict__ Mt) {
  int o = blockIdx.x, c = threadIdx.x;
  __shared__ float a2[32];
  if (c < 32) a2[c] = aw[o * 288 + 256 + c];
  __syncthreads();
  float s = 0.f;
  for (int o2 = 0; o2 < 32; ++o2) s += a2[o2] * G[o2 * 256 + c];
  Mt[o * 256 + c] = gamma[0] * (aw[o * 288 + c] + 4096.f * s) + (o == c ? 1.f : 0.f);
}

// ---------------- P3: folded conv weights w3 (bf16) + cd2 constants ----------------
// w3 layout: idx(tap,cg,kbq,oc,j) = (((tap*16+cg)*4+kbq)*128+oc)*8+j  for channel cf=cg*32+kbq*8+j
__global__ void k_w3(const float* __restrict__ cw, const float* __restrict__ Mt,
                     const float* __restrict__ dvec, u16* __restrict__ w3,
                     float* __restrict__ cd2) {
  int blk = blockIdx.x;                 // 1152 = 9*128
  int tap = blk / 128, oc = blk % 128;
  int tid = threadIdx.x;
  __shared__ float cwl[512];
  for (int c = tid; c < 512; c += 256) cwl[c] = cw[(size_t)(oc * 512 + c) * 9 + tap];
  __syncthreads();
  int c2 = tid;
  float s = 0.f;
  for (int c = 0; c < 256; ++c) s += cwl[c] * Mt[c * 256 + c2];
  {
    int cf = c2;
    int cg = cf >> 5, kbq = (cf >> 3) & 3, j = cf & 7;
    w3[((((tap * 16 + cg) * 4 + kbq) * 128 + oc) << 3) + j] = f2bf(s);
    cf = c2 + 256;
    cg = cf >> 5; kbq = (cf >> 3) & 3; j = cf & 7;
    w3[((((tap * 16 + cg) * 4 + kbq) * 128 + oc) << 3) + j] = f2bf(cwl[c2 + 256]);
  }
  __shared__ float red[4];
  for (int b = 0; b < 4; ++b) {
    float p = cwl[tid] * dvec[b * 256 + tid];   // only channels 0..255 carry d
    p = wave_sum(p);
    if ((tid & 63) == 0) red[tid >> 6] = p;
    __syncthreads();
    if (tid == 0) cd2[(size_t)(b * 128 + oc) * 9 + tap] = red[0] + red[1] + red[2] + red[3];
    __syncthreads();
  }
}

// ---------------- X: build NHWC bf16 xin[b][h][w][512] ----------------
__global__ void k_xin(const float* __restrict__ tgt, const float* __restrict__ prev,
                      u16* __restrict__ xin) {
  int b = blockIdx.x >> 6, h = blockIdx.x & 63;
  __shared__ u16 lt[256 * 66];
  int tid = threadIdx.x;
  const float* tp = tgt + ((size_t)(b * 256) * 64 + h) * 64;
  u16* xp = xin + (((size_t)(b * 64) + h) * 64) * 512;
  // phase A: target rows -> LDS [c][w]
  for (int it = 0; it < 16; ++it) {
    int fi = it * 256 + tid;
    int c = fi >> 4, w4 = fi & 15;
    f32x4 v = *(const f32x4*)(tp + (size_t)c * 4096 + w4 * 4);
    int base = c * 66 + w4 * 4;
    lt[base] = f2bf(v[0]); lt[base + 1] = f2bf(v[1]);
    lt[base + 2] = f2bf(v[2]); lt[base + 3] = f2bf(v[3]);
  }
  __syncthreads();
  // write channels 0..255 transposed (coalesced, channel-contiguous)
  for (int it = 0; it < 8; ++it) {
    int i = it * 256 + tid;
    int c8 = i & 31, w = i >> 5;
    u16x8 v;
#pragma unroll
    for (int k = 0; k < 8; ++k) v[k] = lt[(c8 * 8 + k) * 66 + w];
    *(u16x8*)(xp + (size_t)w * 512 + c8 * 8) = v;
  }
  __syncthreads();
  // phase B: prev upsample -> LDS [cc][w]
  const float* pp = prev + ((size_t)(b * 256) * 32 + (h >> 1)) * 32;
  for (int it = 0; it < 8; ++it) {
    int pi = it * 256 + tid;
    int cc = pi >> 3, wq = pi & 7;
    f32x4 v = *(const f32x4*)(pp + (size_t)cc * 1024 + wq * 4);
    int base = cc * 66 + wq * 8;
    u16 b0 = f2bf(v[0]), b1 = f2bf(v[1]), b2 = f2bf(v[2]), b3 = f2bf(v[3]);
    lt[base] = b0; lt[base + 1] = b0; lt[base + 2] = b1; lt[base + 3] = b1;
    lt[base + 4] = b2; lt[base + 5] = b2; lt[base + 6] = b3; lt[base + 7] = b3;
  }
  __syncthreads();
  // write channels 256..511
  for (int it = 0; it < 8; ++it) {
    int i = it * 256 + tid;
    int c8 = i & 31, w = i >> 5;
    u16x8 v;
#pragma unroll
    for (int k = 0; k < 8; ++k) v[k] = lt[(c8 * 8 + k) * 66 + w];
    *(u16x8*)(xp + (size_t)w * 512 + 256 + c8 * 8) = v;
  }
}

// ---------------- C: tap-decomposed implicit-im2col MFMA conv ----------------
// block = (b, h0). M=128 oc x N=64 px. 8 waves: 4 tile-waves x 2 K-teams.
// team 0: cg 0..7, team 1: cg 8..15; per iter stage BOTH teams' next slice.
// LDS: 2 bufs x 2 teams x (3 rows x 64 px x 32 ch) u16 = 48KB; reduce reuses 32KB.
__global__ __launch_bounds__(512, 2) void k_conv(const u16* __restrict__ xin,
                                                 const u16* __restrict__ w3,
                                                 const float* __restrict__ cd2,
                                                 float* __restrict__ out) {
  __shared__ u16 lds[2 * 2 * 3 * 64 * 32];
  int b = blockIdx.x >> 6, h0 = blockIdx.x & 63;
  int tid = threadIdx.x, l = tid & 63, wv = tid >> 6;
  int team = wv >> 2, wq = wv & 3;
  int wr = wq >> 1, wc = wq & 1;          // wave tile: M 64 x N 32
  const int r = l & 15, kb4 = l >> 4;

  if (h0 == 0)
    for (int i = tid; i < 2048; i += 512) {
#pragma unroll
      for (int bt = 0; bt < 4; ++bt) lds[bt * 6144 + i] = 0;
    }
  if (h0 == 63)
    for (int i = tid; i < 2048; i += 512) {
#pragma unroll
      for (int bt = 0; bt < 4; ++bt) lds[bt * 6144 + 4096 + i] = 0;
    }

  auto STAGE = [&](int buf, int k) {
    u16x8 tmp[3]; int dsts[3]; bool doit[3];
#pragma unroll
    for (int i = 0; i < 3; ++i) {
      int chunk = wv * 3 + i;             // 0..23
      int ts = chunk >= 12, cc = chunk - ts * 12;
      int dy = cc >> 2, qd = cc & 3;
      int grow = h0 - 1 + dy;
      int px = qd * 16 + (l >> 2), sub = l & 3;
      int kb = sub ^ ((px >> 1) & 3);     // source-side swizzle
      int cg = ts * 8 + k;
      doit[i] = ((unsigned)grow < 64u);
      if (doit[i])
        tmp[i] = *(const u16x8*)(xin + ((((size_t)(b * 64) + grow) * 64 + px) * 512 + cg * 32 + kb * 8));
      dsts[i] = (buf * 2 + ts) * 6144 + dy * 2048 + px * 32 + sub * 8;
    }
#pragma unroll
    for (int i = 0; i < 3; ++i)
      if (doit[i]) *(u16x8*)(lds + dsts[i]) = tmp[i];
  };

  f32x4 acc[4][2];
  const f32x4 fz = {0.f, 0.f, 0.f, 0.f};
#pragma unroll
  for (int mf = 0; mf < 4; ++mf)
#pragma unroll
    for (int nf = 0; nf < 2; ++nf) acc[mf][nf] = fz;

  STAGE(0, 0);
  int cur = 0;
  for (int k = 0; k < 8; ++k) {
    __syncthreads();
    if (k < 7) STAGE(cur ^ 1, k + 1);
    const u16* L = lds + (cur * 2 + team) * 6144;
    const int cg = team * 8 + k;
#pragma unroll
    for (int t = 0; t < 9; ++t) {
      const int dy = t / 3, dx = t % 3;
      bf16x8 av[4];
#pragma unroll
      for (int mf = 0; mf < 4; ++mf)
        av[mf] = *(const bf16x8*)(w3 + ((((t * 16 + cg) * 4 + kb4) * 128 + wr * 64 + mf * 16 + r) << 3));
      bf16x8 bv[2];
#pragma unroll
      for (int nf = 0; nf < 2; ++nf) {
        int sx = wc * 32 + nf * 16 + r + dx - 1;
        bf16x8 z = bzero();
        if ((unsigned)sx < 64u) {
          int slot = kb4 ^ ((sx >> 1) & 3); // read-side swizzle
          z = *(const bf16x8*)(L + dy * 2048 + sx * 32 + slot * 8);
        }
        bv[nf] = z;
      }
#pragma unroll
      for (int mf = 0; mf < 4; ++mf)
#pragma unroll
        for (int nf = 0; nf < 2; ++nf)
          acc[mf][nf] = __builtin_amdgcn_mfma_f32_16x16x32_bf16(av[mf], bv[nf], acc[mf][nf], 0, 0, 0);
    }
    cur ^= 1;
  }

  // cross-team reduction through LDS (32KB, reuses staging space)
  __syncthreads();
  float* red = (float*)lds;
  if (team == 1) {
#pragma unroll
    for (int mf = 0; mf < 4; ++mf)
#pragma unroll
      for (int nf = 0; nf < 2; ++nf)
        *(f32x4*)(red + wq * 2048 + (mf * 2 + nf) * 256 + l * 4) = acc[mf][nf];
  }
  __syncthreads();
  if (team == 1) return;
#pragma unroll
  for (int mf = 0; mf < 4; ++mf)
#pragma unroll
    for (int nf = 0; nf < 2; ++nf) {
      f32x4 o = *(const f32x4*)(red + wq * 2048 + (mf * 2 + nf) * 256 + l * 4);
#pragma unroll
      for (int j = 0; j < 4; ++j) acc[mf][nf][j] += o[j];
    }

  // epilogue: add border-masked constant contribution, store y (pre-norm)
  bool dy0v = (h0 > 0), dy2v = (h0 < 63);
#pragma unroll
  for (int mf = 0; mf < 4; ++mf) {
#pragma unroll
    for (int j = 0; j < 4; ++j) {
      int oc = wr * 64 + mf * 16 + kb4 * 4 + j;
      const float* cd = cd2 + (size_t)(b * 128 + oc) * 9;
      float sAll = 0.f, sL = 0.f, sR = 0.f;
#pragma unroll
      for (int dy = 0; dy < 3; ++dy) {
        bool v = (dy == 1) || (dy == 0 ? dy0v : dy2v);
        if (v) {
          sAll += cd[dy * 3] + cd[dy * 3 + 1] + cd[dy * 3 + 2];
          sL += cd[dy * 3];
          sR += cd[dy * 3 + 2];
        }
      }
#pragma unroll
      for (int nf = 0; nf < 2; ++nf) {
        int px = wc * 32 + nf * 16 + r;
        float corr = sAll - (px == 0 ? sL : 0.f) - (px == 63 ? sR : 0.f);
        out[(((size_t)(b * 128 + oc)) * 64 + h0) * 64 + px] = acc[mf][nf][j] + corr;
      }
    }
  }
}

// ---------------- N: in-place instance norm + relu ----------------
__global__ void k_norm(float* __restrict__ out) {
  int plane = blockIdx.x;               // 512 = 4*128
  float* p = out + (size_t)plane * 4096;
  int t = threadIdx.x;
  f32x4 v[4];
  float s = 0.f, s2 = 0.f;
#pragma unroll
  for (int i = 0; i < 4; ++i) {
    v[i] = *(const f32x4*)(p + (i * 256 + t) * 4);
#pragma unroll
    for (int k = 0; k < 4; ++k) { s += v[i][k]; s2 += v[i][k] * v[i][k]; }
  }
  s = wave_sum(s); s2 = wave_sum(s2);
  __shared__ float rs[4], rs2[4];
  if ((t & 63) == 0) { rs[t >> 6] = s; rs2[t >> 6] = s2; }
  __syncthreads();
  float S = rs[0] + rs[1] + rs[2] + rs[3];
  float S2 = rs2[0] + rs2[1] + rs2[2] + rs2[3];
  float mean = S * (1.f / 4096.f);
  float var = S2 * (1.f / 4096.f) - mean * mean;
  float inv = rsqrtf(var + 1e-5f);
#pragma unroll
  for (int i = 0; i < 4; ++i) {
    f32x4 o;
#pragma unroll
    for (int k = 0; k < 4; ++k) {
      float y = (v[i][k] - mean) * inv;
      o[k] = y > 0.f ? y : 0.f;
    }
    *(f32x4*)(p + (i * 256 + t) * 4) = o;
  }
}

extern "C" void kernel_launch(void* const* d_in, const int* in_sizes, int n_in,
                              void* d_out, int out_size, void* d_ws, size_t ws_size,
                              hipStream_t stream) {
  const float* src    = (const float*)d_in[0];
  const float* tgt    = (const float*)d_in[1];
  const float* prev   = (const float*)d_in[2];
  const float* key_w  = (const float*)d_in[3];
  const float* key_b  = (const float*)d_in[4];
  const float* qry_w  = (const float*)d_in[5];
  const float* qry_b  = (const float*)d_in[6];
  const float* lin_w  = (const float*)d_in[7];
  const float* lin_b  = (const float*)d_in[8];
  const float* attn_w = (const float*)d_in[9];
  const float* attn_b = (const float*)d_in[10];
  const float* gamma  = (const float*)d_in[11];
  const float* conv_w = (const float*)d_in[12];
  // d_in[13] = conv_b: dropped — a per-(b,oc) constant cancels under instance norm.

  char* ws = (char*)d_ws;
  size_t off = 0;
  u16*   xin  = (u16*)(ws + off);  off += 16777216;            // 4*64*64*512 bf16
  float* ssum = (float*)(ws + off); off += 4096;               // 4*256
  float* dvec = (float*)(ws + off); off += 4096;               // 4*256
  float* G    = (float*)(ws + off); off += 32768;              // 32*256
  float* Mt   = (float*)(ws + off); off += 262144;             // 256*256
  float* cd2  = (float*)(ws + off); off += 18432;              // 4*128*9
  u16*   w3   = (u16*)(ws + off);  off += 1179648;             // 9*16*4*128*8 bf16
  float* out  = (float*)d_out;

  k_plane_sum<<<1024, 256, 0, stream>>>(src, ssum);
  k_small<<<1, 256, 0, stream>>>(ssum, qry_w, qry_b, key_w, key_b, lin_w, lin_b,
                                 attn_w, attn_b, gamma, dvec, G);
  k_Mt<<<256, 256, 0, stream>>>(attn_w, G, gamma, Mt);
  k_w3<<<1152, 256, 0, stream>>>(conv_w, Mt, dvec, w3, cd2);
  k_xin<<<256, 256, 0, stream>>>(tgt, prev, xin);
  k_conv<<<256, 512, 0, stream>>>(xin, w3, cd2, out);
  k_norm<<<512, 256, 0, stream>>>(out);
}

// Round 3
// 89.367 us; speedup vs baseline: 1.5063x; 1.2129x over previous
//
#include <hip/hip_runtime.h>

typedef unsigned short u16;
typedef __attribute__((ext_vector_type(8))) __bf16 bf16x8;
typedef __attribute__((ext_vector_type(8))) unsigned short u16x8;
typedef __attribute__((ext_vector_type(4))) float f32x4;

__device__ __forceinline__ u16 f2bf(float f) {
  unsigned u = __builtin_bit_cast(unsigned, f);
  unsigned r = u + 0x7fffu + ((u >> 16) & 1u);
  return (u16)(r >> 16);
}

__device__ __forceinline__ float wave_sum(float v) {
#pragma unroll
  for (int o = 32; o; o >>= 1) v += __shfl_xor(v, o, 64);
  return v;
}

__device__ __forceinline__ bf16x8 bzero() {
  bf16x8 z;
#pragma unroll
  for (int i = 0; i < 8; ++i) z[i] = (__bf16)0.0f;
  return z;
}

// ===== K1: fused xin-build (blocks 0..255) + plane sums (blocks 256..1279) =====
__global__ void k_xin_plane(const float* __restrict__ tgt, const float* __restrict__ prev,
                            const float* __restrict__ src,
                            u16* __restrict__ xin, float* __restrict__ ssum) {
  __shared__ u16 lt[256 * 66];
  int tid = threadIdx.x;
  if (blockIdx.x >= 256) {              // ---- plane sum of source_enc ----
    int plane = blockIdx.x - 256;       // 0..1023
    const float* p = src + (size_t)plane * 4096;
    float s = 0.f;
#pragma unroll
    for (int i = 0; i < 4; ++i) {
      f32x4 v = *(const f32x4*)(p + (i * 256 + tid) * 4);
      s += v[0] + v[1] + v[2] + v[3];
    }
    s = wave_sum(s);
    float* red = (float*)lt;
    if ((tid & 63) == 0) red[tid >> 6] = s;
    __syncthreads();
    if (tid == 0) ssum[plane] = red[0] + red[1] + red[2] + red[3];
    return;
  }
  // ---- xin build: NHWC bf16 xin[b][h][w][512] ----
  int b = blockIdx.x >> 6, h = blockIdx.x & 63;
  const float* tp = tgt + ((size_t)(b * 256) * 64 + h) * 64;
  u16* xp = xin + (((size_t)(b * 64) + h) * 64) * 512;
  for (int it = 0; it < 16; ++it) {
    int fi = it * 256 + tid;
    int c = fi >> 4, w4 = fi & 15;
    f32x4 v = *(const f32x4*)(tp + (size_t)c * 4096 + w4 * 4);
    int base = c * 66 + w4 * 4;
    lt[base] = f2bf(v[0]); lt[base + 1] = f2bf(v[1]);
    lt[base + 2] = f2bf(v[2]); lt[base + 3] = f2bf(v[3]);
  }
  __syncthreads();
  for (int it = 0; it < 8; ++it) {
    int i = it * 256 + tid;
    int c8 = i & 31, w = i >> 5;
    u16x8 v;
#pragma unroll
    for (int k = 0; k < 8; ++k) v[k] = lt[(c8 * 8 + k) * 66 + w];
    *(u16x8*)(xp + (size_t)w * 512 + c8 * 8) = v;
  }
  __syncthreads();
  const float* pp = prev + ((size_t)(b * 256) * 32 + (h >> 1)) * 32;
  for (int it = 0; it < 8; ++it) {
    int pi = it * 256 + tid;
    int cc = pi >> 3, wq = pi & 7;
    f32x4 v = *(const f32x4*)(pp + (size_t)cc * 1024 + wq * 4);
    int base = cc * 66 + wq * 8;
    u16 b0 = f2bf(v[0]), b1 = f2bf(v[1]), b2 = f2bf(v[2]), b3 = f2bf(v[3]);
    lt[base] = b0; lt[base + 1] = b0; lt[base + 2] = b1; lt[base + 3] = b1;
    lt[base + 4] = b2; lt[base + 5] = b2; lt[base + 6] = b3; lt[base + 7] = b3;
  }
  __syncthreads();
  for (int it = 0; it < 8; ++it) {
    int i = it * 256 + tid;
    int c8 = i & 31, w = i >> 5;
    u16x8 v;
#pragma unroll
    for (int k = 0; k < 8; ++k) v[k] = lt[(c8 * 8 + k) * 66 + w];
    *(u16x8*)(xp + (size_t)w * 512 + 256 + c8 * 8) = v;
  }
}

// ===== K2: Mt rows (blocks 0..255, G folded via E=A2@Wk) + dvec chain (block 256) =====
__global__ void k_mt_vec(const float* __restrict__ ssum,
                         const float* __restrict__ qw, const float* __restrict__ qb,
                         const float* __restrict__ kw, const float* __restrict__ kb,
                         const float* __restrict__ lw, const float* __restrict__ lb,
                         const float* __restrict__ aw, const float* __restrict__ ab,
                         const float* __restrict__ gamma,
                         float* __restrict__ dvec, float* __restrict__ Mt) {
  int t = threadIdx.x;
  if (blockIdx.x < 256) {               // ---- one Mt row per block ----
    __shared__ float E[32];
    int o = blockIdx.x;
    if (t < 32) {                       // E[a] = sum_o2 A2[o][o2] * Wk[o2][a]
      float s = 0.f;
      for (int o2 = 0; o2 < 32; ++o2) s += aw[o * 288 + 256 + o2] * lw[o2 * 64 + t];
      E[t] = s;
    }
    __syncthreads();
    int c2 = t;
    float s = 0.f;
    for (int a = 0; a < 32; ++a) s += E[a] * kw[a * 256 + c2];
    Mt[o * 256 + c2] = gamma[0] * (aw[o * 288 + c2] + 4096.f * s) + (o == c2 ? 1.f : 0.f);
    return;
  }
  // ---- block 256: qs -> amap -> dvec ----
  __shared__ float qs_l[128], amap_l[128];
  if (t < 128) {
    int b = t >> 5, o = t & 31;
    float s = 4096.f * qb[o];
    for (int c = 0; c < 256; ++c) s += qw[o * 256 + c] * ssum[b * 256 + c];
    qs_l[t] = s;
  }
  __syncthreads();
  if (t < 128) {
    int b = t >> 5, o2 = t & 31;
    float s = 0.f, kt = 0.f;
    for (int o = 0; o < 32; ++o) {
      s += lw[o2 * 64 + 32 + o] * qs_l[b * 32 + o];
      kt += lw[o2 * 64 + o] * kb[o];
    }
    amap_l[t] = 4096.f * (kt + lb[o2]) + s;
  }
  __syncthreads();
  float g = gamma[0];
  for (int i = t; i < 1024; i += 256) {
    int b = i >> 8, c = i & 255;
    float s = ab[c];
    for (int o2 = 0; o2 < 32; ++o2) s += aw[c * 288 + 256 + o2] * amap_l[b * 32 + o2];
    dvec[i] = g * s;
  }
}

// ===== K3: folded conv weights w3 (bf16) + cd2; block = (tap, 8-oc group) =====
// w3 layout: idx(tap,cg,kbq,oc,j) = (((tap*16+cg)*4+kbq)*128+oc)*8+j, channel cf=cg*32+kbq*8+j
__global__ void k_w3(const float* __restrict__ cw, const float* __restrict__ Mt,
                     const float* __restrict__ dvec, u16* __restrict__ w3,
                     float* __restrict__ cd2) {
  __shared__ float cwl[8 * 512];
  __shared__ float part[512];
  int blk = blockIdx.x;                 // 144 = 9*16
  int tap = blk >> 4, ocg = blk & 15;
  int tid = threadIdx.x;                // 512 threads
  for (int e = tid; e < 4096; e += 512) {
    int oc = e >> 9, c = e & 511;
    cwl[e] = cw[(size_t)((ocg * 8 + oc) * 512 + c) * 9 + tap];
  }
  __syncthreads();
  int wv = tid >> 6, l = tid & 63;      // wv = oc (0..7), lane covers 4 cf
  int c2 = l * 4;
  f32x4 acc = {0.f, 0.f, 0.f, 0.f};
  for (int c = 0; c < 256; ++c) {
    float wc = cwl[wv * 512 + c];
    f32x4 m = *(const f32x4*)(Mt + c * 256 + c2);
#pragma unroll
    for (int j = 0; j < 4; ++j) acc[j] += wc * m[j];
  }
  int ocf = ocg * 8 + wv;
#pragma unroll
  for (int j2 = 0; j2 < 4; ++j2) {
    int cf = c2 + j2;
    int cg = cf >> 5, kbq = (cf >> 3) & 3, j = cf & 7;
    w3[((((tap * 16 + cg) * 4 + kbq) * 128 + ocf) << 3) + j] = f2bf(acc[j2]);
    cf = 256 + c2 + j2;
    cg = cf >> 5; kbq = (cf >> 3) & 3; j = cf & 7;
    w3[((((tap * 16 + cg) * 4 + kbq) * 128 + ocf) << 3) + j] = f2bf(cwl[wv * 512 + cf]);
  }
  // cd2[(b*128+oc)*9+tap] = sum_{c<256} cw[oc][c][tap] * dvec[b][c]
  {
    int b = tid >> 7, oc = (tid >> 4) & 7, cp = tid & 15;
    float s = 0.f;
#pragma unroll
    for (int i = 0; i < 16; ++i) s += cwl[oc * 512 + cp * 16 + i] * dvec[b * 256 + cp * 16 + i];
    part[tid] = s;
  }
  __syncthreads();
  if (tid < 32) {
    int b = tid >> 3, oc = tid & 7;
    float s = 0.f;
#pragma unroll
    for (int cp = 0; cp < 16; ++cp) s += part[b * 128 + oc * 16 + cp];
    cd2[(size_t)(b * 128 + ocg * 8 + oc) * 9 + tap] = s;
  }
}

// ===== K4: conv. block=(b,h0). 8 waves = 4 cg-teams x 2 wr. wave: M64 x N64. =====
// LDS: 2 bufs x 4 teams x (3 rows x 64 px x 32 ch) u16 = 96KB (reduction reuses it).
__global__ __launch_bounds__(512, 2) void k_conv(const u16* __restrict__ xin,
                                                 const u16* __restrict__ w3,
                                                 const float* __restrict__ cd2,
                                                 float* __restrict__ out) {
  __shared__ u16 lds[49152];
  int b = blockIdx.x >> 6, h0 = blockIdx.x & 63;
  int tid = threadIdx.x, l = tid & 63, wv = tid >> 6;
  int team = wv >> 1, wr = wv & 1;      // wave: oc half wr, all 64 px, cg quarter
  const int r = l & 15, kb4 = l >> 4;

  if (h0 == 0)
    for (int i = tid; i < 2048; i += 512) {
#pragma unroll
      for (int bt = 0; bt < 8; ++bt) lds[bt * 6144 + i] = 0;
    }
  if (h0 == 63)
    for (int i = tid; i < 2048; i += 512) {
#pragma unroll
      for (int bt = 0; bt < 8; ++bt) lds[bt * 6144 + 4096 + i] = 0;
    }

  // chunk c = wv*6+i -> ts = wv>>1 (own team), cc = (wv&1)*6+i
  u16x8 stmp[6]; int sdst[6]; bool sdo[6];
  auto STAGE_LOAD = [&](int k) {
#pragma unroll
    for (int i = 0; i < 6; ++i) {
      int cc = (wv & 1) * 6 + i;        // 0..11
      int dy = cc >> 2, qd = cc & 3;
      int grow = h0 - 1 + dy;
      int px = qd * 16 + (l >> 2), sub = l & 3;
      int kb = sub ^ ((px >> 1) & 3);   // source-side swizzle
      int cg = team * 4 + k;
      sdo[i] = ((unsigned)grow < 64u);
      if (sdo[i])
        stmp[i] = *(const u16x8*)(xin + ((((size_t)(b * 64) + grow) * 64 + px) * 512 + cg * 32 + kb * 8));
      sdst[i] = dy * 2048 + px * 32 + sub * 8;
    }
  };
  auto STAGE_WRITE = [&](int buf) {
    int base = (buf * 4 + team) * 6144;
#pragma unroll
    for (int i = 0; i < 6; ++i)
      if (sdo[i]) *(u16x8*)(lds + base + sdst[i]) = stmp[i];
  };

  f32x4 acc[4][4];
  const f32x4 fz = {0.f, 0.f, 0.f, 0.f};
#pragma unroll
  for (int mf = 0; mf < 4; ++mf)
#pragma unroll
    for (int nf = 0; nf < 4; ++nf) acc[mf][nf] = fz;

  STAGE_LOAD(0);
  STAGE_WRITE(0);
  __syncthreads();
  int cur = 0;
  for (int k = 0; k < 4; ++k) {
    if (k < 3) STAGE_LOAD(k + 1);
    const u16* L = lds + (cur * 4 + team) * 6144;
    const int cg = team * 4 + k;
#pragma unroll
    for (int t = 0; t < 9; ++t) {
      const int dy = t / 3, dx = t % 3;
      bf16x8 av[4];
#pragma unroll
      for (int mf = 0; mf < 4; ++mf)
        av[mf] = *(const bf16x8*)(w3 + ((((t * 16 + cg) * 4 + kb4) * 128 + wr * 64 + mf * 16 + r) << 3));
      bf16x8 bv[4];
#pragma unroll
      for (int nf = 0; nf < 4; ++nf) {
        int sx = nf * 16 + r + dx - 1;
        bf16x8 z = bzero();
        if ((unsigned)sx < 64u) {
          int slot = kb4 ^ ((sx >> 1) & 3); // read-side swizzle
          z = *(const bf16x8*)(L + dy * 2048 + sx * 32 + slot * 8);
        }
        bv[nf] = z;
      }
#pragma unroll
      for (int mf = 0; mf < 4; ++mf)
#pragma unroll
        for (int nf = 0; nf < 4; ++nf)
          acc[mf][nf] = __builtin_amdgcn_mfma_f32_16x16x32_bf16(av[mf], bv[nf], acc[mf][nf], 0, 0, 0);
    }
    if (k < 3) STAGE_WRITE(cur ^ 1);
    __syncthreads();
    cur ^= 1;
  }

  // cross-team reduction: waves 2..7 write 16KB regions (96KB total), waves 0..1 add
  float* red = (float*)lds;
  if (wv >= 2) {
    int region = wv - 2;
#pragma unroll
    for (int mf = 0; mf < 4; ++mf)
#pragma unroll
      for (int nf = 0; nf < 4; ++nf)
        *(f32x4*)(red + region * 4096 + (mf * 4 + nf) * 256 + l * 4) = acc[mf][nf];
  }
  __syncthreads();
  if (wv >= 2) return;
#pragma unroll
  for (int tp = 0; tp < 3; ++tp) {
    int region = tp * 2 + wr;
#pragma unroll
    for (int mf = 0; mf < 4; ++mf)
#pragma unroll
      for (int nf = 0; nf < 4; ++nf) {
        f32x4 o = *(const f32x4*)(red + region * 4096 + (mf * 4 + nf) * 256 + l * 4);
#pragma unroll
        for (int j = 0; j < 4; ++j) acc[mf][nf][j] += o[j];
      }
  }

  // epilogue: border-masked constant correction + store pre-norm y
  bool dy0v = (h0 > 0), dy2v = (h0 < 63);
#pragma unroll
  for (int mf = 0; mf < 4; ++mf) {
#pragma unroll
    for (int j = 0; j < 4; ++j) {
      int oc = wr * 64 + mf * 16 + kb4 * 4 + j;
      const float* cd = cd2 + (size_t)(b * 128 + oc) * 9;
      float sAll = 0.f, sL = 0.f, sR = 0.f;
#pragma unroll
      for (int dy = 0; dy < 3; ++dy) {
        bool v = (dy == 1) || (dy == 0 ? dy0v : dy2v);
        if (v) {
          sAll += cd[dy * 3] + cd[dy * 3 + 1] + cd[dy * 3 + 2];
          sL += cd[dy * 3];
          sR += cd[dy * 3 + 2];
        }
      }
#pragma unroll
      for (int nf = 0; nf < 4; ++nf) {
        int px = nf * 16 + r;
        float corr = sAll - (px == 0 ? sL : 0.f) - (px == 63 ? sR : 0.f);
        out[(((size_t)(b * 128 + oc)) * 64 + h0) * 64 + px] = acc[mf][nf][j] + corr;
      }
    }
  }
}

// ===== K5: in-place instance norm + relu =====
__global__ void k_norm(float* __restrict__ out) {
  int plane = blockIdx.x;               // 512 = 4*128
  float* p = out + (size_t)plane * 4096;
  int t = threadIdx.x;
  f32x4 v[4];
  float s = 0.f, s2 = 0.f;
#pragma unroll
  for (int i = 0; i < 4; ++i) {
    v[i] = *(const f32x4*)(p + (i * 256 + t) * 4);
#pragma unroll
    for (int k = 0; k < 4; ++k) { s += v[i][k]; s2 += v[i][k] * v[i][k]; }
  }
  s = wave_sum(s); s2 = wave_sum(s2);
  __shared__ float rs[4], rs2[4];
  if ((t & 63) == 0) { rs[t >> 6] = s; rs2[t >> 6] = s2; }
  __syncthreads();
  float S = rs[0] + rs[1] + rs[2] + rs[3];
  float S2 = rs2[0] + rs2[1] + rs2[2] + rs2[3];
  float mean = S * (1.f / 4096.f);
  float var = S2 * (1.f / 4096.f) - mean * mean;
  float inv = rsqrtf(var + 1e-5f);
#pragma unroll
  for (int i = 0; i < 4; ++i) {
    f32x4 o;
#pragma unroll
    for (int k = 0; k < 4; ++k) {
      float y = (v[i][k] - mean) * inv;
      o[k] = y > 0.f ? y : 0.f;
    }
    *(f32x4*)(p + (i * 256 + t) * 4) = o;
  }
}

extern "C" void kernel_launch(void* const* d_in, const int* in_sizes, int n_in,
                              void* d_out, int out_size, void* d_ws, size_t ws_size,
                              hipStream_t stream) {
  const float* src    = (const float*)d_in[0];
  const float* tgt    = (const float*)d_in[1];
  const float* prev   = (const float*)d_in[2];
  const float* key_w  = (const float*)d_in[3];
  const float* key_b  = (const float*)d_in[4];
  const float* qry_w  = (const float*)d_in[5];
  const float* qry_b  = (const float*)d_in[6];
  const float* lin_w  = (const float*)d_in[7];
  const float* lin_b  = (const float*)d_in[8];
  const float* attn_w = (const float*)d_in[9];
  const float* attn_b = (const float*)d_in[10];
  const float* gamma  = (const float*)d_in[11];
  const float* conv_w = (const float*)d_in[12];
  // d_in[13] = conv_b: dropped — per-(b,oc) constant cancels under instance norm.

  char* ws = (char*)d_ws;
  size_t off = 0;
  u16*   xin  = (u16*)(ws + off);  off += 16777216;            // 4*64*64*512 bf16
  float* ssum = (float*)(ws + off); off += 4096;               // 4*256
  float* dvec = (float*)(ws + off); off += 4096;               // 4*256
  float* Mt   = (float*)(ws + off); off += 262144;             // 256*256
  float* cd2  = (float*)(ws + off); off += 18432;              // 4*128*9
  u16*   w3   = (u16*)(ws + off);  off += 1179648;             // 9*16*4*128*8 bf16
  float* out  = (float*)d_out;

  k_xin_plane<<<1280, 256, 0, stream>>>(tgt, prev, src, xin, ssum);
  k_mt_vec<<<257, 256, 0, stream>>>(ssum, qry_w, qry_b, key_w, key_b, lin_w, lin_b,
                                    attn_w, attn_b, gamma, dvec, Mt);
  k_w3<<<144, 512, 0, stream>>>(conv_w, Mt, dvec, w3, cd2);
  k_conv<<<256, 512, 0, stream>>>(xin, w3, cd2, out);
  k_norm<<<512, 256, 0, stream>>>(out);
}